// Round 14
// baseline (180.053 us; speedup 1.0000x reference)
//
#include <hip/hip_runtime.h>

typedef __bf16 bf16x8 __attribute__((ext_vector_type(8)));
typedef float f32x4 __attribute__((ext_vector_type(4)));
typedef float f32x16 __attribute__((ext_vector_type(16)));

#define MFMA16(a, b, c) __builtin_amdgcn_mfma_f32_16x16x32_bf16(a, b, c, 0, 0, 0)
#define MFMA32(a, b, c) __builtin_amdgcn_mfma_f32_32x32x16_bf16(a, b, c, 0, 0, 0)
#define GLDS16(g, l)                                                              \
  __builtin_amdgcn_global_load_lds((const __attribute__((address_space(1))) void*)(g), \
                                   (__attribute__((address_space(3))) void*)(l), 16, 0, 0)

static __device__ __forceinline__ unsigned cvt_pk_bf16(float lo, float hi) {
  unsigned r;
  asm("v_cvt_pk_bf16_f32 %0, %1, %2" : "=v"(r) : "v"(lo), "v"(hi));
  return r;
}
// v_permlane32_swap_b32: a'[l<32]=a[l], a'[l>=32]=b[l-32], b'[l<32]=a[l+32], b'[l>=32]=b[l]
static __device__ __forceinline__ void permswap(unsigned& a, unsigned& b) {
  asm("v_permlane32_swap_b32 %0, %1" : "+v"(a), "+v"(b));
}

// ---------------- prep: cvt x->bf16 (blocks 0-4095) + transpose both weights ----------------
__global__ __launch_bounds__(256) void prep_kernel(const float* __restrict__ x,
                                                   __bf16* __restrict__ xb,
                                                   const float* __restrict__ Wq,
                                                   __bf16* __restrict__ WqT,
                                                   const float* __restrict__ Wo,
                                                   __bf16* __restrict__ WoT) {
  __shared__ float tile[32][33];
  int bid = blockIdx.x;
  int tid = threadIdx.x;
  if (bid < 4096) {
    int i = bid * 256 + tid;
    float4 v = ((const float4*)x)[i];
    union { __bf16 b[4]; uint2 u; } t;
    t.b[0] = (__bf16)v.x; t.b[1] = (__bf16)v.y;
    t.b[2] = (__bf16)v.z; t.b[3] = (__bf16)v.w;
    ((uint2*)xb)[i] = t.u;
    return;
  }
  const int Kd = 1024;
  int b2 = bid - 4096;
  int bx = b2 & 127;
  int k0 = (b2 >> 7) * 32;
  const float* W; __bf16* WT; int Nd, n0;
  if (bx < 96) { W = Wq; WT = WqT; Nd = 3072; n0 = bx * 32; }
  else         { W = Wo; WT = WoT; Nd = 1024; n0 = (bx - 96) * 32; }
  int kk = tid >> 3, nn = (tid & 7) * 4;
  float4 v = *(const float4*)&W[(size_t)(k0 + kk) * Nd + n0 + nn];
  tile[kk][nn] = v.x; tile[kk][nn + 1] = v.y;
  tile[kk][nn + 2] = v.z; tile[kk][nn + 3] = v.w;
  __syncthreads();
  int n2 = tid >> 3, k2 = (tid & 7) * 4;
  union { __bf16 b[4]; uint2 u; } t;
  t.b[0] = (__bf16)tile[k2][n2];
  t.b[1] = (__bf16)tile[k2 + 1][n2];
  t.b[2] = (__bf16)tile[k2 + 2][n2];
  t.b[3] = (__bf16)tile[k2 + 3][n2];
  *(uint2*)&WT[(size_t)(n0 + n2) * Kd + k0 + k2] = t.u;
}

// ---------------- GEMM: C[M,N] = A[M,1024] @ BT[N,1024]^T + bias ----------------
// Round-4 verified core + XCD 2D-chunk swizzle (round-9 verified: FETCH 28.8->20.5MB).
// bf16 path (gemm1, NT=128): vectorized C-store. Round-9 counters: WRITE_SIZE 57MB
// vs 25MB output (32B partial-line bf16 stores -> RMW). Epilogue stages each wave's
// 16x64 tile in LDS scratch (16 rows x 72 stride; waves 0-1 in dead As, 2-3 in Bs)
// and stores full 128B lines. ALL quads write (no exec-masked LDS writes), order
// pinned with sched_barrier(0) at both phase edges; same-wave DS FIFO provides the
// data ordering (precedent: the session's verified wave-private P round-trip).
template <bool OUT_F32, int NT, int CBY>
__global__ __launch_bounds__(256) void gemm_kernel(const __bf16* __restrict__ A,
                                                   const __bf16* __restrict__ BT,
                                                   const float* __restrict__ bias,
                                                   void* __restrict__ Cout, int N,
                                                   int qn, float qs) {
  const int K = 1024;
  const int NJ = NT / 32;
  __shared__ __align__(16) __bf16 As[128 * 32];
  __shared__ __align__(16) __bf16 Bs[NT * 32];
  int tid = threadIdx.x;
  int wave = tid >> 6, lane = tid & 63;
  int quad = lane >> 4, l16 = lane & 15;
  int id = blockIdx.x;
  int xcd = id & 7, r = id >> 3;
  int m0 = ((xcd & 3) * 8 + (r & 7)) * 128;
  int n0 = ((xcd >> 2) * CBY + (r >> 3)) * NT;
  int wm = (wave >> 1) * 64, wn = (wave & 1) * (NT / 2);

  int srow = tid >> 2, scol = (tid & 3) * 8;
  const __bf16* aptr = A + (size_t)(m0 + srow) * K + scol;
  const __bf16* bptr = BT + (size_t)(n0 + srow) * K + scol;
  __bf16* asl = &As[(size_t)wave * 512];
  __bf16* bsl = &Bs[(size_t)wave * 512];

  f32x4 acc[4][NJ] = {};
  for (int k0 = 0; k0 < K; k0 += 32) {
    GLDS16(aptr + k0, asl);
    GLDS16(aptr + (size_t)64 * K + k0, asl + 2048);
    GLDS16(bptr + k0, bsl);
    if (NT == 128) GLDS16(bptr + (size_t)64 * K + k0, bsl + 2048);
    __syncthreads();
    bf16x8 af[4], bf[NJ];
    for (int i = 0; i < 4; i++)
      af[i] = *(bf16x8*)&As[(wm + i * 16 + l16) * 32 + quad * 8];
    for (int j = 0; j < NJ; j++)
      bf[j] = *(bf16x8*)&Bs[(wn + j * 16 + l16) * 32 + quad * 8];
    for (int i = 0; i < 4; i++)
      for (int j = 0; j < NJ; j++)
        acc[i][j] = MFMA16(af[i], bf[j], acc[i][j]);
    __syncthreads();
  }
  // K-loop ends with __syncthreads(): all As/Bs LDS traffic and GLDS writes retired.
  if constexpr (OUT_F32) {
    for (int j = 0; j < NJ; j++) {
      int col = n0 + wn + j * 16 + l16;
      float bv = bias[col];
      float sc = (col < qn) ? qs : 1.0f;
      for (int i = 0; i < 4; i++) {
        int rowb = m0 + wm + i * 16 + quad * 4;
        for (int r2 = 0; r2 < 4; r2++)
          ((float*)Cout)[(size_t)(rowb + r2) * N + col] =
              (acc[i][j][r2] + bv) * sc;
      }
    }
  } else {
    // NT==128 path. Per-wave scratch: 16 rows x 72 bf16 = 2304B, 16B-aligned.
    float bv[NJ], sc[NJ];
    for (int j = 0; j < NJ; j++) {
      int col = n0 + wn + j * 16 + l16;
      bv[j] = bias[col];
      sc[j] = (col < qn) ? qs : 1.0f;
    }
    __bf16* S = (wave & 2) ? &Bs[(wave & 1) * 1152] : &As[(wave & 1) * 1152];
    int lr = lane >> 3, ch = lane & 7;
    for (int i = 0; i < 4; i++) {
      int rowb16 = m0 + wm + i * 16;
      // all lanes write: S row quad*4+r2 (0..15), col j*16+l16 (0..63)
      for (int j = 0; j < NJ; j++)
        for (int r2 = 0; r2 < 4; r2++)
          S[(quad * 4 + r2) * 72 + j * 16 + l16] =
              (__bf16)((acc[i][j][r2] + bv[j]) * sc[j]);
      __builtin_amdgcn_sched_barrier(0);  // pin: writes precede reads
      // read rows lr and lr+8 (16B/lane), store full 128B lines
      uint4 v0 = *(uint4*)&S[lr * 72 + ch * 8];
      uint4 v1 = *(uint4*)&S[(8 + lr) * 72 + ch * 8];
      *(uint4*)&((__bf16*)Cout)[(size_t)(rowb16 + lr) * N + n0 + wn + ch * 8] = v0;
      *(uint4*)&((__bf16*)Cout)[(size_t)(rowb16 + 8 + lr) * N + n0 + wn + ch * 8] =
          v1;
      __builtin_amdgcn_sched_barrier(0);  // pin: reads precede next i's writes
    }
  }
}

// ---------------- transpose V slice of qkv -> Vt [b][h][d][t] ----------------
__global__ __launch_bounds__(256) void transpose_v_kernel(const __bf16* __restrict__ qkv,
                                                          __bf16* __restrict__ Vt) {
  const int T = 2048, C3 = 3072;
  __shared__ __align__(16) __bf16 tile[64][72];
  int t0 = blockIdx.x * 64;
  int h = blockIdx.y, b = blockIdx.z;
  int tid = threadIdx.x;
  int tt = tid >> 2, c = (tid & 3) * 16;
  const __bf16* src = qkv + (size_t)(b * T + t0 + tt) * C3 + 2048 + h * 64 + c;
  *(uint4*)&tile[tt][c] = *(const uint4*)src;
  *(uint4*)&tile[tt][c + 8] = *(const uint4*)(src + 8);
  __syncthreads();
  int dd = tid >> 2, t2 = (tid & 3) * 16;
  union { __bf16 b_[16]; uint4 u[2]; } o;
  for (int i = 0; i < 16; i++) o.b_[i] = tile[t2 + i][dd];
  __bf16* dst = Vt + ((size_t)(b * 16 + h) * 64 + dd) * T + t0 + t2;
  *(uint4*)dst = o.u[0];
  *(uint4*)(dst + 8) = o.u[1];
}

// ---------------- flash attention: T15 pipeline + 2nd-order XOR swizzle ----------------
struct AttnState {
  const char* lbase;
  char* wdst;
  int dK, dV;
  int lb[2][4];
};

template <int KRD, int VRD, int KST, int VST, bool DO_KST>
__device__ __forceinline__ void attn_iter(const AttnState& st, const __bf16* kg,
                                          const __bf16* vg, const bf16x8 (&qf)[4],
                                          const f32x16* sIN, f32x16* sOUT, f32x16& o0,
                                          f32x16& o1, float& rs) {
  __syncthreads();
  if constexpr (DO_KST) {
    GLDS16(kg, st.wdst + KST);
    GLDS16(kg + st.dK, st.wdst + KST + 4096);
  }
  GLDS16(vg, st.wdst + VST);
  GLDS16(vg + st.dV, st.wdst + VST + 4096);

  bf16x8 kf[2][4], vf[2][4];
#pragma unroll
  for (int rb = 0; rb < 2; rb++)
#pragma unroll
    for (int ds = 0; ds < 4; ds++)
      kf[rb][ds] = *(const bf16x8*)(st.lbase + st.lb[rb][ds] + KRD);
#pragma unroll
  for (int db = 0; db < 2; db++)
#pragma unroll
    for (int k2 = 0; k2 < 4; k2++)
      vf[db][k2] = *(const bf16x8*)(st.lbase + st.lb[db][k2] + VRD);

  f32x16 s0 = {}, s1 = {};
#pragma unroll
  for (int ds = 0; ds < 4; ds++) {
    s0 = MFMA32(kf[0][ds], qf[ds], s0);
    s1 = MFMA32(kf[1][ds], qf[ds], s1);
  }
  sOUT[0] = s0;
  sOUT[1] = s1;

  bf16x8 ap[4];
#pragma unroll
  for (int kb = 0; kb < 2; kb++) {
    float pv[16];
#pragma unroll
    for (int r = 0; r < 16; r++) {
      pv[r] = __builtin_amdgcn_exp2f(sIN[kb][r]);
      rs += pv[r];
    }
#pragma unroll
    for (int hf = 0; hf < 2; hf++) {
      unsigned w0 = cvt_pk_bf16(pv[hf * 8 + 0], pv[hf * 8 + 1]);
      unsigned w1 = cvt_pk_bf16(pv[hf * 8 + 2], pv[hf * 8 + 3]);
      unsigned w2 = cvt_pk_bf16(pv[hf * 8 + 4], pv[hf * 8 + 5]);
      unsigned w3 = cvt_pk_bf16(pv[hf * 8 + 6], pv[hf * 8 + 7]);
      permswap(w0, w2);
      permswap(w1, w3);
      union { unsigned u[4]; bf16x8 v; } pk;
      pk.u[0] = w0; pk.u[1] = w1; pk.u[2] = w2; pk.u[3] = w3;
      ap[kb * 2 + hf] = pk.v;
    }
  }

#pragma unroll
  for (int k2 = 0; k2 < 4; k2++) {
    o0 = MFMA32(ap[k2], vf[0][k2], o0);
    o1 = MFMA32(ap[k2], vf[1][k2], o1);
  }
}

__global__ __launch_bounds__(256, 2) void attn_kernel(const __bf16* __restrict__ qkv,
                                                      const __bf16* __restrict__ Vt,
                                                      __bf16* __restrict__ O) {
  const int T = 2048, C3 = 3072;
  int p = blockIdx.x * 4 + (blockIdx.y >> 4);
  int b = p >> 4, h = p & 15;
  int q0 = (blockIdx.y & 15) * 128;

  int tid = threadIdx.x, wave = tid >> 6, lane = tid & 63;
  int l32 = lane & 31, hi = lane >> 5;

  __shared__ __align__(16) __bf16 KV[4][64 * 64];

  const __bf16* qp = qkv + (size_t)(b * T + q0 + wave * 32 + l32) * C3 + h * 64;
  bf16x8 qf[4];
#pragma unroll
  for (int ds = 0; ds < 4; ds++)
    qf[ds] = *(const bf16x8*)(qp + ds * 16 + hi * 8);

  const __bf16* kbase = qkv + (size_t)(b * T) * C3 + 1024 + h * 64;
  const __bf16* vbase = Vt + (size_t)(b * 16 + h) * 64 * T;

  int srow = wave * 8 + (lane >> 3);
  int sx1 = ((lane & 7) ^ (lane >> 3) ^ wave) * 8;
  int sx2 = sx1 ^ 32;
  const __bf16* ksrc = kbase + (size_t)srow * C3 + sx1;
  const __bf16* vsrc = vbase + (size_t)srow * T + sx1;

  AttnState st;
  st.lbase = (const char*)&KV[0][0];
  st.wdst = (char*)&KV[0][0] + wave * 1024;
  st.dK = 32 * C3 + (sx2 - sx1);
  st.dV = 32 * T + (sx2 - sx1);
#pragma unroll
  for (int rb = 0; rb < 2; rb++)
#pragma unroll
    for (int c4 = 0; c4 < 4; c4++)
      st.lb[rb][c4] =
          ((rb * 32 + l32) * 64 +
           (((c4 * 2 + hi) ^ (l32 & 7) ^ (l32 >> 3) ^ (rb * 4)) * 8)) * 2;

  f32x16 o0 = {}, o1 = {};
  f32x16 sA2[2], sB2[2];
  float rs = 0.0f;

  GLDS16(ksrc, st.wdst + 0);
  GLDS16(ksrc + st.dK, st.wdst + 4096);
  GLDS16(vsrc, st.wdst + 8192);
  GLDS16(vsrc + st.dV, st.wdst + 8192 + 4096);
  GLDS16(ksrc + (size_t)64 * C3, st.wdst + 16384);
  GLDS16(ksrc + (size_t)64 * C3 + st.dK, st.wdst + 16384 + 4096);
  __syncthreads();

  {
    bf16x8 kf[2][4];
#pragma unroll
    for (int rb = 0; rb < 2; rb++)
#pragma unroll
      for (int ds = 0; ds < 4; ds++)
        kf[rb][ds] = *(const bf16x8*)(st.lbase + st.lb[rb][ds] + 0);
    f32x16 s0 = {}, s1 = {};
#pragma unroll
    for (int ds = 0; ds < 4; ds++) {
      s0 = MFMA32(kf[0][ds], qf[ds], s0);
      s1 = MFMA32(kf[1][ds], qf[ds], s1);
    }
    sA2[0] = s0;
    sA2[1] = s1;
  }

  const size_t kstep = (size_t)64 * C3;
  const __bf16* kg = ksrc + 2 * kstep;
  const __bf16* vg = vsrc + 64;

  for (int tp = 0; tp < 15; ++tp) {
    attn_iter<16384, 8192, 0, 24576, true>(st, kg, vg, qf, sA2, sB2, o0, o1, rs);
    kg += kstep; vg += 64;
    attn_iter<0, 24576, 16384, 8192, true>(st, kg, vg, qf, sB2, sA2, o0, o1, rs);
    kg += kstep; vg += 64;
  }
  attn_iter<16384, 8192, 0, 24576, false>(st, kg, vg, qf, sA2, sB2, o0, o1, rs);

  {
    __syncthreads();
    bf16x8 vf[2][4];
#pragma unroll
    for (int db = 0; db < 2; db++)
#pragma unroll
      for (int k2 = 0; k2 < 4; k2++)
        vf[db][k2] = *(const bf16x8*)(st.lbase + st.lb[db][k2] + 24576);
    bf16x8 ap[4];
#pragma unroll
    for (int kb = 0; kb < 2; kb++) {
      float pv[16];
#pragma unroll
      for (int r = 0; r < 16; r++) {
        pv[r] = __builtin_amdgcn_exp2f(sB2[kb][r]);
        rs += pv[r];
      }
#pragma unroll
      for (int hf = 0; hf < 2; hf++) {
        unsigned w0 = cvt_pk_bf16(pv[hf * 8 + 0], pv[hf * 8 + 1]);
        unsigned w1 = cvt_pk_bf16(pv[hf * 8 + 2], pv[hf * 8 + 3]);
        unsigned w2 = cvt_pk_bf16(pv[hf * 8 + 4], pv[hf * 8 + 5]);
        unsigned w3 = cvt_pk_bf16(pv[hf * 8 + 6], pv[hf * 8 + 7]);
        permswap(w0, w2);
        permswap(w1, w3);
        union { unsigned u[4]; bf16x8 v; } pk;
        pk.u[0] = w0; pk.u[1] = w1; pk.u[2] = w2; pk.u[3] = w3;
        ap[kb * 2 + hf] = pk.v;
      }
    }
#pragma unroll
    for (int k2 = 0; k2 < 4; k2++) {
      o0 = MFMA32(ap[k2], vf[0][k2], o0);
      o1 = MFMA32(ap[k2], vf[1][k2], o1);
    }
  }

  unsigned xu = __float_as_uint(rs), yu = __float_as_uint(rs);
  permswap(xu, yu);
  float inv = 1.0f / (__uint_as_float(xu) + __uint_as_float(yu));
  float invv[16];
#pragma unroll
  for (int r = 0; r < 16; r++)
    invv[r] = __shfl(inv, (r & 3) + 8 * (r >> 2) + 4 * hi);

  __bf16* ob = O + (size_t)(b * T + q0 + wave * 32) * 1024 + h * 64 + l32;
#pragma unroll
  for (int r = 0; r < 16; r++) {
    int row = (r & 3) + 8 * (r >> 2) + 4 * hi;
    ob[(size_t)row * 1024] = (__bf16)(o0[r] * invv[r]);
    ob[(size_t)row * 1024 + 32] = (__bf16)(o1[r] * invv[r]);
  }
}

// ---------------- launch ----------------
extern "C" void kernel_launch(void* const* d_in, const int* in_sizes, int n_in,
                              void* d_out, int out_size, void* d_ws, size_t ws_size,
                              hipStream_t stream) {
  const float* x = (const float*)d_in[0];      // [2,2048,1024]
  const float* W_qkv = (const float*)d_in[1];  // [1024,3072]
  const float* b_qkv = (const float*)d_in[2];  // [3072]
  const float* W_out = (const float*)d_in[3];  // [1024,1024]
  const float* b_out = (const float*)d_in[4];  // [1024]
  float* out = (float*)d_out;                  // [2,2048,1024] f32

  char* ws = (char*)d_ws;
  __bf16* WqkvT = (__bf16*)(ws);               // [3072][1024]  6 MB
  __bf16* WoT = (__bf16*)(ws + 6291456);       // [1024][1024]  2 MB
  __bf16* xb = (__bf16*)(ws + 8388608);        // [4096][1024]  8 MB
  __bf16* qkvb = (__bf16*)(ws + 16777216);     // [4096][3072] 24 MB
  __bf16* Vt = (__bf16*)(ws + 41943040);       // [2][16][64][2048] 8 MB
  __bf16* attnb = xb;  // xb dead after gemm1; reuse for attention output

  const float cs = 0.125f * 1.44269504089f;  // 1/sqrt(64) * log2(e)

  prep_kernel<<<8192, 256, 0, stream>>>(x, xb, W_qkv, WqkvT, W_out, WoT);
  gemm_kernel<false, 128, 12><<<768, 256, 0, stream>>>(xb, WqkvT, b_qkv, qkvb, 3072,
                                                       1024, cs);
  transpose_v_kernel<<<dim3(32, 16, 2), 256, 0, stream>>>(qkvb, Vt);
  attn_kernel<<<dim3(8, 64), 256, 0, stream>>>(qkvb, Vt, attnb);
  gemm_kernel<true, 64, 8><<<512, 256, 0, stream>>>(attnb, WoT, b_out, out, 1024,
                                                    0, 1.0f);
}

// Round 16
// 176.127 us; speedup vs baseline: 1.0223x; 1.0223x over previous
//
#include <hip/hip_runtime.h>

typedef __bf16 bf16x8 __attribute__((ext_vector_type(8)));
typedef float f32x4 __attribute__((ext_vector_type(4)));
typedef float f32x16 __attribute__((ext_vector_type(16)));

#define MFMA16(a, b, c) __builtin_amdgcn_mfma_f32_16x16x32_bf16(a, b, c, 0, 0, 0)
#define MFMA32(a, b, c) __builtin_amdgcn_mfma_f32_32x32x16_bf16(a, b, c, 0, 0, 0)
#define GLDS16(g, l)                                                              \
  __builtin_amdgcn_global_load_lds((const __attribute__((address_space(1))) void*)(g), \
                                   (__attribute__((address_space(3))) void*)(l), 16, 0, 0)

static __device__ __forceinline__ unsigned cvt_pk_bf16(float lo, float hi) {
  unsigned r;
  asm("v_cvt_pk_bf16_f32 %0, %1, %2" : "=v"(r) : "v"(lo), "v"(hi));
  return r;
}
// v_permlane32_swap_b32: a'[l<32]=a[l], a'[l>=32]=b[l-32], b'[l<32]=a[l+32], b'[l>=32]=b[l]
static __device__ __forceinline__ void permswap(unsigned& a, unsigned& b) {
  asm("v_permlane32_swap_b32 %0, %1" : "+v"(a), "+v"(b));
}

// ---------------- prep: cvt x->bf16 (blocks 0-4095) + transpose both weights ----------------
__global__ __launch_bounds__(256) void prep_kernel(const float* __restrict__ x,
                                                   __bf16* __restrict__ xb,
                                                   const float* __restrict__ Wq,
                                                   __bf16* __restrict__ WqT,
                                                   const float* __restrict__ Wo,
                                                   __bf16* __restrict__ WoT) {
  __shared__ float tile[32][33];
  int bid = blockIdx.x;
  int tid = threadIdx.x;
  if (bid < 4096) {
    int i = bid * 256 + tid;
    float4 v = ((const float4*)x)[i];
    union { __bf16 b[4]; uint2 u; } t;
    t.b[0] = (__bf16)v.x; t.b[1] = (__bf16)v.y;
    t.b[2] = (__bf16)v.z; t.b[3] = (__bf16)v.w;
    ((uint2*)xb)[i] = t.u;
    return;
  }
  const int Kd = 1024;
  int b2 = bid - 4096;
  int bx = b2 & 127;
  int k0 = (b2 >> 7) * 32;
  const float* W; __bf16* WT; int Nd, n0;
  if (bx < 96) { W = Wq; WT = WqT; Nd = 3072; n0 = bx * 32; }
  else         { W = Wo; WT = WoT; Nd = 1024; n0 = (bx - 96) * 32; }
  int kk = tid >> 3, nn = (tid & 7) * 4;
  float4 v = *(const float4*)&W[(size_t)(k0 + kk) * Nd + n0 + nn];
  tile[kk][nn] = v.x; tile[kk][nn + 1] = v.y;
  tile[kk][nn + 2] = v.z; tile[kk][nn + 3] = v.w;
  __syncthreads();
  int n2 = tid >> 3, k2 = (tid & 7) * 4;
  union { __bf16 b[4]; uint2 u; } t;
  t.b[0] = (__bf16)tile[k2][n2];
  t.b[1] = (__bf16)tile[k2 + 1][n2];
  t.b[2] = (__bf16)tile[k2 + 2][n2];
  t.b[3] = (__bf16)tile[k2 + 3][n2];
  *(uint2*)&WT[(size_t)(n0 + n2) * Kd + k0 + k2] = t.u;
}

// ---------------- GEMM: C[M,N] = A[M,1024] @ BT[N,1024]^T + bias ----------------
// Round-4 verified core + XCD 2D-chunk swizzle (round-9 verified: FETCH 28.8->20.5MB,
// total 180.3->176.5us). 1D grid; id&7 ~ XCD; each XCD owns an 8(M) x CBY(N) chunk
// of tiles so its A/B panels stay L2-resident.
template <bool OUT_F32, int NT, int CBY>
__global__ __launch_bounds__(256) void gemm_kernel(const __bf16* __restrict__ A,
                                                   const __bf16* __restrict__ BT,
                                                   const float* __restrict__ bias,
                                                   void* __restrict__ Cout, int N,
                                                   int qn, float qs) {
  const int K = 1024;
  const int NJ = NT / 32;
  __shared__ __align__(16) __bf16 As[128 * 32];
  __shared__ __align__(16) __bf16 Bs[NT * 32];
  int tid = threadIdx.x;
  int wave = tid >> 6, lane = tid & 63;
  int quad = lane >> 4, l16 = lane & 15;
  int id = blockIdx.x;
  int xcd = id & 7, r = id >> 3;
  int m0 = ((xcd & 3) * 8 + (r & 7)) * 128;
  int n0 = ((xcd >> 2) * CBY + (r >> 3)) * NT;
  int wm = (wave >> 1) * 64, wn = (wave & 1) * (NT / 2);

  int srow = tid >> 2, scol = (tid & 3) * 8;
  const __bf16* aptr = A + (size_t)(m0 + srow) * K + scol;
  const __bf16* bptr = BT + (size_t)(n0 + srow) * K + scol;
  __bf16* asl = &As[(size_t)wave * 512];
  __bf16* bsl = &Bs[(size_t)wave * 512];

  f32x4 acc[4][NJ] = {};
  for (int k0 = 0; k0 < K; k0 += 32) {
    GLDS16(aptr + k0, asl);
    GLDS16(aptr + (size_t)64 * K + k0, asl + 2048);
    GLDS16(bptr + k0, bsl);
    if (NT == 128) GLDS16(bptr + (size_t)64 * K + k0, bsl + 2048);
    __syncthreads();
    bf16x8 af[4], bf[NJ];
    for (int i = 0; i < 4; i++)
      af[i] = *(bf16x8*)&As[(wm + i * 16 + l16) * 32 + quad * 8];
    for (int j = 0; j < NJ; j++)
      bf[j] = *(bf16x8*)&Bs[(wn + j * 16 + l16) * 32 + quad * 8];
    for (int i = 0; i < 4; i++)
      for (int j = 0; j < NJ; j++)
        acc[i][j] = MFMA16(af[i], bf[j], acc[i][j]);
    __syncthreads();
  }
  for (int j = 0; j < NJ; j++) {
    int col = n0 + wn + j * 16 + l16;
    float bv = bias[col];
    float sc = (col < qn) ? qs : 1.0f;
    for (int i = 0; i < 4; i++) {
      int rowb = m0 + wm + i * 16 + quad * 4;
      for (int r2 = 0; r2 < 4; r2++) {
        float v = (acc[i][j][r2] + bv) * sc;
        if (OUT_F32)
          ((float*)Cout)[(size_t)(rowb + r2) * N + col] = v;
        else
          ((__bf16*)Cout)[(size_t)(rowb + r2) * N + col] = (__bf16)v;
      }
    }
  }
}

// ---------------- transpose V slice of qkv -> Vt [b][h][d][t] ----------------
__global__ __launch_bounds__(256) void transpose_v_kernel(const __bf16* __restrict__ qkv,
                                                          __bf16* __restrict__ Vt) {
  const int T = 2048, C3 = 3072;
  __shared__ __align__(16) __bf16 tile[64][72];
  int t0 = blockIdx.x * 64;
  int h = blockIdx.y, b = blockIdx.z;
  int tid = threadIdx.x;
  int tt = tid >> 2, c = (tid & 3) * 16;
  const __bf16* src = qkv + (size_t)(b * T + t0 + tt) * C3 + 2048 + h * 64 + c;
  *(uint4*)&tile[tt][c] = *(const uint4*)src;
  *(uint4*)&tile[tt][c + 8] = *(const uint4*)(src + 8);
  __syncthreads();
  int dd = tid >> 2, t2 = (tid & 3) * 16;
  union { __bf16 b_[16]; uint4 u[2]; } o;
  for (int i = 0; i < 16; i++) o.b_[i] = tile[t2 + i][dd];
  __bf16* dst = Vt + ((size_t)(b * 16 + h) * 64 + dd) * T + t0 + t2;
  *(uint4*)dst = o.u[0];
  *(uint4*)(dst + 8) = o.u[1];
}

// ---------------- flash attention: T15 pipeline + 2nd-order XOR swizzle ----------------
// Swapped QK^T (S^T = mfma(K,Q)); in-register softmax via cvt_pk+permlane32_swap.
// Pipeline: iter t runs QK(t+1) [MFMA] then softmax(t) [VALU] then PV(t) [MFMA].
// LDS: single arena KV[4] = {K0,V0,K1,V1}, compile-time buffer selection.
// Swizzle slot = logical ^ (row&7) ^ ((row>>3)&7), applied on both sides.
struct AttnState {
  const char* lbase;
  char* wdst;
  int dK, dV;
  int lb[2][4];
};

template <int KRD, int VRD, int KST, int VST, bool DO_KST>
__device__ __forceinline__ void attn_iter(const AttnState& st, const __bf16* kg,
                                          const __bf16* vg, const bf16x8 (&qf)[4],
                                          const f32x16* sIN, f32x16* sOUT, f32x16& o0,
                                          f32x16& o1, float& rs) {
  __syncthreads();
  if constexpr (DO_KST) {
    GLDS16(kg, st.wdst + KST);
    GLDS16(kg + st.dK, st.wdst + KST + 4096);
  }
  GLDS16(vg, st.wdst + VST);
  GLDS16(vg + st.dV, st.wdst + VST + 4096);

  bf16x8 kf[2][4], vf[2][4];
#pragma unroll
  for (int rb = 0; rb < 2; rb++)
#pragma unroll
    for (int ds = 0; ds < 4; ds++)
      kf[rb][ds] = *(const bf16x8*)(st.lbase + st.lb[rb][ds] + KRD);
#pragma unroll
  for (int db = 0; db < 2; db++)
#pragma unroll
    for (int k2 = 0; k2 < 4; k2++)
      vf[db][k2] = *(const bf16x8*)(st.lbase + st.lb[db][k2] + VRD);

  f32x16 s0 = {}, s1 = {};
#pragma unroll
  for (int ds = 0; ds < 4; ds++) {
    s0 = MFMA32(kf[0][ds], qf[ds], s0);
    s1 = MFMA32(kf[1][ds], qf[ds], s1);
  }
  sOUT[0] = s0;
  sOUT[1] = s1;

  bf16x8 ap[4];
#pragma unroll
  for (int kb = 0; kb < 2; kb++) {
    float pv[16];
#pragma unroll
    for (int r = 0; r < 16; r++) {
      pv[r] = __builtin_amdgcn_exp2f(sIN[kb][r]);
      rs += pv[r];
    }
#pragma unroll
    for (int hf = 0; hf < 2; hf++) {
      unsigned w0 = cvt_pk_bf16(pv[hf * 8 + 0], pv[hf * 8 + 1]);
      unsigned w1 = cvt_pk_bf16(pv[hf * 8 + 2], pv[hf * 8 + 3]);
      unsigned w2 = cvt_pk_bf16(pv[hf * 8 + 4], pv[hf * 8 + 5]);
      unsigned w3 = cvt_pk_bf16(pv[hf * 8 + 6], pv[hf * 8 + 7]);
      permswap(w0, w2);
      permswap(w1, w3);
      union { unsigned u[4]; bf16x8 v; } pk;
      pk.u[0] = w0; pk.u[1] = w1; pk.u[2] = w2; pk.u[3] = w3;
      ap[kb * 2 + hf] = pk.v;
    }
  }

#pragma unroll
  for (int k2 = 0; k2 < 4; k2++) {
    o0 = MFMA32(ap[k2], vf[0][k2], o0);
    o1 = MFMA32(ap[k2], vf[1][k2], o1);
  }
}

__global__ __launch_bounds__(256, 2) void attn_kernel(const __bf16* __restrict__ qkv,
                                                      const __bf16* __restrict__ Vt,
                                                      __bf16* __restrict__ O) {
  const int T = 2048, C3 = 3072;
  int p = blockIdx.x * 4 + (blockIdx.y >> 4);
  int b = p >> 4, h = p & 15;
  int q0 = (blockIdx.y & 15) * 128;

  int tid = threadIdx.x, wave = tid >> 6, lane = tid & 63;
  int l32 = lane & 31, hi = lane >> 5;

  __shared__ __align__(16) __bf16 KV[4][64 * 64];

  const __bf16* qp = qkv + (size_t)(b * T + q0 + wave * 32 + l32) * C3 + h * 64;
  bf16x8 qf[4];
#pragma unroll
  for (int ds = 0; ds < 4; ds++)
    qf[ds] = *(const bf16x8*)(qp + ds * 16 + hi * 8);

  const __bf16* kbase = qkv + (size_t)(b * T) * C3 + 1024 + h * 64;
  const __bf16* vbase = Vt + (size_t)(b * 16 + h) * 64 * T;

  int srow = wave * 8 + (lane >> 3);
  int sx1 = ((lane & 7) ^ (lane >> 3) ^ wave) * 8;
  int sx2 = sx1 ^ 32;
  const __bf16* ksrc = kbase + (size_t)srow * C3 + sx1;
  const __bf16* vsrc = vbase + (size_t)srow * T + sx1;

  AttnState st;
  st.lbase = (const char*)&KV[0][0];
  st.wdst = (char*)&KV[0][0] + wave * 1024;
  st.dK = 32 * C3 + (sx2 - sx1);
  st.dV = 32 * T + (sx2 - sx1);
#pragma unroll
  for (int rb = 0; rb < 2; rb++)
#pragma unroll
    for (int c4 = 0; c4 < 4; c4++)
      st.lb[rb][c4] =
          ((rb * 32 + l32) * 64 +
           (((c4 * 2 + hi) ^ (l32 & 7) ^ (l32 >> 3) ^ (rb * 4)) * 8)) * 2;

  f32x16 o0 = {}, o1 = {};
  f32x16 sA2[2], sB2[2];
  float rs = 0.0f;

  GLDS16(ksrc, st.wdst + 0);
  GLDS16(ksrc + st.dK, st.wdst + 4096);
  GLDS16(vsrc, st.wdst + 8192);
  GLDS16(vsrc + st.dV, st.wdst + 8192 + 4096);
  GLDS16(ksrc + (size_t)64 * C3, st.wdst + 16384);
  GLDS16(ksrc + (size_t)64 * C3 + st.dK, st.wdst + 16384 + 4096);
  __syncthreads();

  {
    bf16x8 kf[2][4];
#pragma unroll
    for (int rb = 0; rb < 2; rb++)
#pragma unroll
      for (int ds = 0; ds < 4; ds++)
        kf[rb][ds] = *(const bf16x8*)(st.lbase + st.lb[rb][ds] + 0);
    f32x16 s0 = {}, s1 = {};
#pragma unroll
    for (int ds = 0; ds < 4; ds++) {
      s0 = MFMA32(kf[0][ds], qf[ds], s0);
      s1 = MFMA32(kf[1][ds], qf[ds], s1);
    }
    sA2[0] = s0;
    sA2[1] = s1;
  }

  const size_t kstep = (size_t)64 * C3;
  const __bf16* kg = ksrc + 2 * kstep;
  const __bf16* vg = vsrc + 64;

  for (int tp = 0; tp < 15; ++tp) {
    attn_iter<16384, 8192, 0, 24576, true>(st, kg, vg, qf, sA2, sB2, o0, o1, rs);
    kg += kstep; vg += 64;
    attn_iter<0, 24576, 16384, 8192, true>(st, kg, vg, qf, sB2, sA2, o0, o1, rs);
    kg += kstep; vg += 64;
  }
  attn_iter<16384, 8192, 0, 24576, false>(st, kg, vg, qf, sA2, sB2, o0, o1, rs);

  {
    __syncthreads();
    bf16x8 vf[2][4];
#pragma unroll
    for (int db = 0; db < 2; db++)
#pragma unroll
      for (int k2 = 0; k2 < 4; k2++)
        vf[db][k2] = *(const bf16x8*)(st.lbase + st.lb[db][k2] + 24576);
    bf16x8 ap[4];
#pragma unroll
    for (int kb = 0; kb < 2; kb++) {
      float pv[16];
#pragma unroll
      for (int r = 0; r < 16; r++) {
        pv[r] = __builtin_amdgcn_exp2f(sB2[kb][r]);
        rs += pv[r];
      }
#pragma unroll
      for (int hf = 0; hf < 2; hf++) {
        unsigned w0 = cvt_pk_bf16(pv[hf * 8 + 0], pv[hf * 8 + 1]);
        unsigned w1 = cvt_pk_bf16(pv[hf * 8 + 2], pv[hf * 8 + 3]);
        unsigned w2 = cvt_pk_bf16(pv[hf * 8 + 4], pv[hf * 8 + 5]);
        unsigned w3 = cvt_pk_bf16(pv[hf * 8 + 6], pv[hf * 8 + 7]);
        permswap(w0, w2);
        permswap(w1, w3);
        union { unsigned u[4]; bf16x8 v; } pk;
        pk.u[0] = w0; pk.u[1] = w1; pk.u[2] = w2; pk.u[3] = w3;
        ap[kb * 2 + hf] = pk.v;
      }
    }
#pragma unroll
    for (int k2 = 0; k2 < 4; k2++) {
      o0 = MFMA32(ap[k2], vf[0][k2], o0);
      o1 = MFMA32(ap[k2], vf[1][k2], o1);
    }
  }

  unsigned xu = __float_as_uint(rs), yu = __float_as_uint(rs);
  permswap(xu, yu);
  float inv = 1.0f / (__uint_as_float(xu) + __uint_as_float(yu));
  float invv[16];
#pragma unroll
  for (int r = 0; r < 16; r++)
    invv[r] = __shfl(inv, (r & 3) + 8 * (r >> 2) + 4 * hi);

  __bf16* ob = O + (size_t)(b * T + q0 + wave * 32) * 1024 + h * 64 + l32;
#pragma unroll
  for (int r = 0; r < 16; r++) {
    int row = (r & 3) + 8 * (r >> 2) + 4 * hi;
    ob[(size_t)row * 1024] = (__bf16)(o0[r] * invv[r]);
    ob[(size_t)row * 1024 + 32] = (__bf16)(o1[r] * invv[r]);
  }
}

// ---------------- launch ----------------
extern "C" void kernel_launch(void* const* d_in, const int* in_sizes, int n_in,
                              void* d_out, int out_size, void* d_ws, size_t ws_size,
                              hipStream_t stream) {
  const float* x = (const float*)d_in[0];      // [2,2048,1024]
  const float* W_qkv = (const float*)d_in[1];  // [1024,3072]
  const float* b_qkv = (const float*)d_in[2];  // [3072]
  const float* W_out = (const float*)d_in[3];  // [1024,1024]
  const float* b_out = (const float*)d_in[4];  // [1024]
  float* out = (float*)d_out;                  // [2,2048,1024] f32

  char* ws = (char*)d_ws;
  __bf16* WqkvT = (__bf16*)(ws);               // [3072][1024]  6 MB
  __bf16* WoT = (__bf16*)(ws + 6291456);       // [1024][1024]  2 MB
  __bf16* xb = (__bf16*)(ws + 8388608);        // [4096][1024]  8 MB
  __bf16* qkvb = (__bf16*)(ws + 16777216);     // [4096][3072] 24 MB
  __bf16* Vt = (__bf16*)(ws + 41943040);       // [2][16][64][2048] 8 MB
  __bf16* attnb = xb;  // xb dead after gemm1; reuse for attention output

  const float cs = 0.125f * 1.44269504089f;  // 1/sqrt(64) * log2(e)

  prep_kernel<<<8192, 256, 0, stream>>>(x, xb, W_qkv, WqkvT, W_out, WoT);
  gemm_kernel<false, 128, 12><<<768, 256, 0, stream>>>(xb, WqkvT, b_qkv, qkvb, 3072,
                                                       1024, cs);
  transpose_v_kernel<<<dim3(32, 16, 2), 256, 0, stream>>>(qkvb, Vt);
  attn_kernel<<<dim3(8, 64), 256, 0, stream>>>(qkvb, Vt, attnb);
  gemm_kernel<true, 64, 8><<<512, 256, 0, stream>>>(attnb, WoT, b_out, out, 1024,
                                                    0, 1.0f);
}